// Round 16
// baseline (155.184 us; speedup 1.0000x reference)
//
#include <hip/hip_runtime.h>
#include <math.h>

#define Bn 16
#define Ln 2048
#define Gn 8
#define Pn 8
#define Kn 64
#define CLAMP_V 15.0f

#define BPB 64              // blocks per batch-chain
#define NTH 512             // 8 waves
#define NWV (NTH / 64)
#define LPB (Ln / BPB)      // 32 columns per block per batch
#define LPW (LPB / NWV)     // 4 columns per wave per batch
#define PK  (Pn * Kn)

// d_ws: part[Gn][Bn][BPB][Pn] qwords = {MAGIC(g)<<32 | f32 partial} (512KB).
// Harness 0xAA poison never matches a tag -> tagged partial IS the arrival
// signal; no init pass, no counters (round-10-proven protocol).
#define MAGIC(g) (0x5EED0000u | (unsigned)(g))

typedef unsigned long long ull;

// wave64 sum via DPP (VALU pipe, no LDS). Total lands in lane 63.
__device__ __forceinline__ float wave_sum64(float x) {
#define DPP_ADD(ctrl) \
    x += __int_as_float(__builtin_amdgcn_update_dpp(0, __float_as_int(x), ctrl, 0xf, 0xf, true))
    DPP_ADD(0x111);  // row_shr:1
    DPP_ADD(0x112);  // row_shr:2
    DPP_ADD(0x114);  // row_shr:4
    DPP_ADD(0x118);  // row_shr:8
    DPP_ADD(0x142);  // row_bcast:15
    DPP_ADD(0x143);  // row_bcast:31
#undef DPP_ADD
    return x;
}

template <int IMM>
__device__ __forceinline__ float swz_xor(float v) {
    return v + __int_as_float(__builtin_amdgcn_ds_swizzle(__float_as_int(v), IMM));
}
__device__ __forceinline__ ull ld_rlx64(const ull* p) {
    return __hip_atomic_load(p, __ATOMIC_RELAXED, __HIP_MEMORY_SCOPE_AGENT);
}
__device__ __forceinline__ void st_rlx64(ull* p, ull v) {
    __hip_atomic_store(p, v, __ATOMIC_RELAXED, __HIP_MEMORY_SCOPE_AGENT);
}

// ---- compute one (batch, group): dn-sharing inner loop (r14-proven), wave
// reduce, internal barrier, wave-0 fold + tagged publish. Uniform call. ----
__device__ __forceinline__ void do_cp(
    int c, int lane, int wv, int a0k, const int* sig,
    const float4* s_xp, const unsigned short* s_idx, float (*s_part)[Pn],
    const float* xpb, const float* xnb, ull* pg, unsigned magic) {

    const float px = xpb[a0k * 3 + 0], py = xpb[a0k * 3 + 1], pz = xpb[a0k * 3 + 2];
    const int   jn = s_idx[a0k];
    const float nkx = xnb[jn * 3 + 0], nky = xnb[jn * 3 + 1], nkz = xnb[jn * 3 + 2];

    unsigned short jl[LPW];
    #pragma unroll
    for (int i = 0; i < LPW; i++) jl[i] = s_idx[c * LPB + wv * LPW + i];

    float acc[Pn];
    #pragma unroll
    for (int p = 0; p < Pn; p++) acc[p] = 0.0f;

    #pragma unroll
    for (int i = 0; i < LPW; i++) {
        const int il = wv * LPW + i;
        const int l  = c * LPB + il;
        if (__ballot(a0k == l)) continue;      // colmask: l in base set (rare)

        const float4 q = s_xp[il];
        const int    j = jl[i];
        const float mx = xnb[j * 3 + 0], my = xnb[j * 3 + 1], mz = xnb[j * 3 + 2];

        const float dx = px - q.x, dy = py - q.y, dz = pz - q.z;
        const float dp = __builtin_amdgcn_sqrtf(dx * dx + dy * dy + dz * dz);
        const float ex = nkx - mx, ey = nky - my, ez = nkz - mz;
        const float dn = __builtin_amdgcn_sqrtf(ex * ex + ey * ey + ez * ez);

        #pragma unroll
        for (int p = 0; p < Pn; p++) {
            const float dns = __int_as_float(
                __builtin_amdgcn_ds_bpermute(sig[p], __float_as_int(dn)));
            const float e = dp - dns;
            acc[p] += fminf(e * e, CLAMP_V);
        }
    }

    #pragma unroll
    for (int p = 0; p < Pn; p++) {
        const float v = wave_sum64(acc[p]);
        if (lane == 63) s_part[wv][p] = v;
    }
    __syncthreads();   // s_part complete (uniform barrier)

    if (wv == 0) {
        float v = s_part[lane >> 3][lane & 7];   // lane = (q<<3)|p
        v = swz_xor<0x201F>(v);
        v = swz_xor<0x401F>(v);
        v += __shfl(v, lane + 32, 64);
        if (lane < 8)
            st_rlx64(&pg[c * Pn + lane],
                     ((ull)magic << 32) | (ull)__float_as_uint(v));
    }
}

// ---- wave-0: poll 64x8 tagged qwords (8/lane), fold, argmin, update idx ----
__device__ __forceinline__ void poll_upd(
    const int* ag, unsigned short* s_idx, const ull* pg, unsigned magic, int lane) {
    ull q[8];
    unsigned rm = 0;
    for (;;) {
        #pragma unroll
        for (int i = 0; i < 8; i++) {
            if (!(rm & (1u << i))) {
                q[i] = ld_rlx64(pg + lane + 64 * i);
                if ((unsigned)(q[i] >> 32) == magic) rm |= 1u << i;
            }
        }
        if (__ballot(rm != 0xFFu) == 0ull) break;
        __builtin_amdgcn_s_sleep(1);
    }
    float v = 0.0f;
    #pragma unroll
    for (int i = 0; i < 8; i++) v += __uint_as_float((unsigned)q[i]);
    v = swz_xor<0x201F>(v);          // fold c bit (lane bit 3)
    v = swz_xor<0x401F>(v);          // fold c bit (lane bit 4)
    v += __shfl(v, lane + 32, 64);   // fold c bit (lane bit 5)
    float best = __shfl(v, 0, 64);
    int   bj   = 0;
    #pragma unroll
    for (int p = 1; p < Pn; p++) {
        const float t = __shfl(v, p, 64);
        if (t < best) { best = t; bj = p; }   // strict < == jnp.argmin tie rule
    }
    const unsigned short oldv = s_idx[ag[bj * Kn + lane]];  // gather then
    s_idx[ag[lane]] = oldv;                                 // scatter (in-wave)
}

// ---------------------------------------------------------------------------
// Dual-batch interleave: each block advances TWO independent batch chains
// (b, b+8) in alternation, so every publish has a full opposite-chain compute
// (~1.7us) to propagate before its poll — polls hit on arrival, removing the
// ~3.5us/group exposed publish->observe latency of the single-chain ordering
// (r15 falsified the skew-width theory; r11 failed because speculation within
// a DEPENDENT chain needs corrections — independent chains need none).
// sig/s_inv/colmask are batch-independent (shared); s_all dropped (r13: LDS-
// izing the gathers was neutral). LDS ~13KB; launch_bounds(,8) caps VGPR at
// 64 -> >=4 blocks/CU capacity for the 2 needed (residency slack, r8 lesson).
// ---------------------------------------------------------------------------
__global__ __launch_bounds__(NTH, 8) void fused_kernel(
    const float* __restrict__ xpred, const float* __restrict__ xnat,
    const int* __restrict__ mask_in, const int* __restrict__ autom,
    float* __restrict__ out_x, float* __restrict__ out_m,
    ull* __restrict__ part) {

    const int tid  = threadIdx.x;
    const int lane = tid & 63;
    const int wv   = tid >> 6;
    const int bA   = blockIdx.x >> 6;         // pair id 0..7 -> batches (bA, bA+8)
    const int bB   = bA + 8;
    const int c    = blockIdx.x & (BPB - 1);

    __shared__ unsigned short s_idxA[Ln];     // 4KB
    __shared__ unsigned short s_idxB[Ln];     // 4KB
    __shared__ unsigned char  s_inv[2][Ln];   // 4KB: node -> base pos (shared)
    __shared__ float4         s_xpA[LPB];     // 512B
    __shared__ float4         s_xpB[LPB];     // 512B
    __shared__ float          s_part[NWV][Pn];

    const float* xpA = xpred + (size_t)bA * Ln * 3;
    const float* xpB = xpred + (size_t)bB * Ln * 3;
    const float* xnA = xnat  + (size_t)bA * Ln * 3;
    const float* xnB = xnat  + (size_t)bB * Ln * 3;

    // ---- prologue ----
    for (int l = tid; l < Ln; l += NTH) {
        s_idxA[l] = (unsigned short)l;
        s_idxB[l] = (unsigned short)l;
    }
    if (wv == 0) {                           // lanes 0..31: A, 32..63: B
        const int half = lane >> 5, col = lane & 31;
        const int l = c * LPB + col;
        const float* xp = half ? xpB : xpA;
        const float4 v = make_float4(xp[l * 3 + 0], xp[l * 3 + 1], xp[l * 3 + 2], 0.0f);
        if (half) s_xpB[col] = v; else s_xpA[col] = v;
    } else if (wv == 2) {
        s_inv[0][autom[lane]] = (unsigned char)lane;
    }
    __syncthreads();

    int a0k = autom[lane];
    int sig[Pn];
    #pragma unroll
    for (int p = 0; p < Pn; p++) sig[p] = 4 * (int)s_inv[0][autom[p * Kn + lane]];

    do_cp(c, lane, wv, a0k, sig, s_xpA, s_idxA, s_part, xpA, xnA,
          part + (size_t)(0 * Bn + bA) * BPB * Pn, MAGIC(0));
    __syncthreads();   // wave0's fold of s_part(A) done before B overwrites
    do_cp(c, lane, wv, a0k, sig, s_xpB, s_idxB, s_part, xpB, xnB,
          part + (size_t)(0 * Bn + bB) * BPB * Pn, MAGIC(0));

    #pragma unroll 1
    for (int g = 0; g < Gn; g++) {
        const bool hn  = (g < Gn - 1);
        const int* ag  = autom + g * PK;
        const int* ag1 = autom + (g + 1) * PK;    // only deref'd when hn

        if (wv == 0)
            poll_upd(ag, s_idxA, part + (size_t)(g * Bn + bA) * BPB * Pn,
                     MAGIC(g), lane);
        if (hn && wv == 2)
            s_inv[(g + 1) & 1][ag1[lane]] = (unsigned char)lane;
        __syncthreads();   // s_idxA + s_inv[nxt] visible; s_part(B) consumed

        if (hn) {
            #pragma unroll
            for (int p = 0; p < Pn; p++)
                sig[p] = 4 * (int)s_inv[(g + 1) & 1][ag1[p * Kn + lane]];
            a0k = ag1[lane];
            do_cp(c, lane, wv, a0k, sig, s_xpA, s_idxA, s_part, xpA, xnA,
                  part + (size_t)((g + 1) * Bn + bA) * BPB * Pn, MAGIC(g + 1));
        }

        if (wv == 0)
            poll_upd(ag, s_idxB, part + (size_t)(g * Bn + bB) * BPB * Pn,
                     MAGIC(g), lane);
        __syncthreads();   // s_idxB visible; s_part(A) consumed by wave0

        if (hn) {
            do_cp(c, lane, wv, a0k, sig, s_xpB, s_idxB, s_part, xpB, xnB,
                  part + (size_t)((g + 1) * Bn + bB) * BPB * Pn, MAGIC(g + 1));
        }
    }

    // ---- epilogue: threads 0..255 -> batch A, 256..511 -> batch B ----
    const int t = tid & 255;
    const unsigned short* si = (tid < 256) ? s_idxA : s_idxB;
    const float* xn = (tid < 256) ? xnA : xnB;
    const int    bo = (tid < 256) ? bA : bB;
    const int    l0 = c * LPB;
    if (t < LPB * 3) {
        const int ll = t / 3, coord = t % 3;
        const int l  = l0 + ll;
        const int j  = si[l];
        out_x[((size_t)bo * Ln + l) * 3 + coord] = xn[j * 3 + coord];
    } else if (t < LPB * 4) {
        const int l = l0 + (t - LPB * 3);
        const int j = si[l];
        out_m[(size_t)bo * Ln + l] = (float)mask_in[(size_t)bo * Ln + j];
    }
}

// ---------------------------------------------------------------------------
extern "C" void kernel_launch(void* const* d_in, const int* in_sizes, int n_in,
                              void* d_out, int out_size, void* d_ws, size_t ws_size,
                              hipStream_t stream) {
    const float* xpred   = (const float*)d_in[0];  // (B,L,3) f32
    const float* xnat_in = (const float*)d_in[1];  // (B,L,3) f32
    const int*   mask_in = (const int*)  d_in[2];  // (B,L) bool -> int32
    const int*   autom   = (const int*)  d_in[3];  // (G,P,K) -> int32

    float* out_x = (float*)d_out;          // (B,L,3)
    float* out_m = out_x + Bn * Ln * 3;    // (B,L) as float 0/1

    ull* part = (ull*)d_ws;                // Gn*Bn*BPB*Pn qwords (512KB)

    fused_kernel<<<8 * BPB, NTH, 0, stream>>>(
        xpred, xnat_in, mask_in, autom, out_x, out_m, part);
}

// Round 17
// 124.202 us; speedup vs baseline: 1.2494x; 1.2494x over previous
//
#include <hip/hip_runtime.h>
#include <math.h>

#define Bn 16
#define Ln 2048
#define Gn 8
#define Pn 8
#define Kn 64
#define CLAMP_V 15.0f

#define BPB 32              // blocks per batch
#define NTH 512             // 8 waves
#define NWV (NTH / 64)
#define LPB (Ln / BPB)      // 64 columns per block
#define LPW (LPB / NWV)     // 8 columns per wave
#define PK  (Pn * Kn)

// d_ws: part[Gn][Bn][BPB][Pn] qwords = {MAGIC(g)<<32 | f32 partial} (128KB).
// Harness 0xAA poison never matches a tag -> tagged partial IS the arrival
// signal; no init pass, no counters in global (round-10-proven protocol).
#define MAGIC(g) (0x5EED0000u | (unsigned)(g))

typedef unsigned long long ull;

// wave64 sum via DPP (VALU pipe, no LDS). Total lands in lane 63.
__device__ __forceinline__ float wave_sum64(float x) {
#define DPP_ADD(ctrl) \
    x += __int_as_float(__builtin_amdgcn_update_dpp(0, __float_as_int(x), ctrl, 0xf, 0xf, true))
    DPP_ADD(0x111);  // row_shr:1
    DPP_ADD(0x112);  // row_shr:2
    DPP_ADD(0x114);  // row_shr:4
    DPP_ADD(0x118);  // row_shr:8
    DPP_ADD(0x142);  // row_bcast:15
    DPP_ADD(0x143);  // row_bcast:31
#undef DPP_ADD
    return x;
}

template <int IMM>
__device__ __forceinline__ float swz_xor(float v) {
    return v + __int_as_float(__builtin_amdgcn_ds_swizzle(__float_as_int(v), IMM));
}
__device__ __forceinline__ ull ld_rlx64(const ull* p) {
    return __hip_atomic_load(p, __ATOMIC_RELAXED, __HIP_MEMORY_SCOPE_AGENT);
}
__device__ __forceinline__ void st_rlx64(ull* p, ull v) {
    __hip_atomic_store(p, v, __ATOMIC_RELAXED, __HIP_MEMORY_SCOPE_AGENT);
}

// ---------------------------------------------------------------------------
// r14 base (64us best: dn-sharing bpermute loop + tagged-qword sync; r16's
// dual-chain interleave REVERTED — max-of-64 skew + chain coupling regressed
// to 103us). Two critical-path cuts vs r14:
//  1. LAST-ARRIVER PUBLISH: each wave writes its s_part row then does an
//     acq_rel LDS counter add; the wave that sees old==NWV-1 folds+publishes
//     immediately — no barrier, no wave-0 fold round trip before publish.
//  2. PREFETCH+PATCH (r9/r10-proven): jl/nk (s_idx-dependent) are gathered
//     BEFORE the barrier with the pre-update map, concurrent with wave-0's
//     poll. The race with wave-0's s_idx scatter only corrupts rows stamped
//     this group; the post-barrier patch re-reads exactly those. ONE barrier
//     per group instead of two.
// s_all dropped (r13: LDS-izing gathers neutral); all 8 inverse tables built
// in the prologue (wave w builds group w's). LDS ~23.5KB, launch_bounds(,6)
// caps VGPR <=~84 -> 3 blocks/CU capacity for grid 512 (slack, r8 lesson).
// ---------------------------------------------------------------------------
__global__ __launch_bounds__(NTH, 6) void fused_kernel(
    const float* __restrict__ xpred, const float* __restrict__ xnat,
    const int* __restrict__ mask_in, const int* __restrict__ autom,
    float* __restrict__ out_x, float* __restrict__ out_m,
    ull* __restrict__ part) {

    const int tid  = threadIdx.x;
    const int lane = tid & 63;       // k = base position
    const int wv   = tid >> 6;       // wave 0..7
    const int b    = blockIdx.x >> 5;         // batch
    const int c    = blockIdx.x & (BPB - 1);  // chunk within batch

    __shared__ unsigned short s_idx[Ln];      // 4KB: node -> current row
    __shared__ signed char    s_stamp[Ln];    // 2KB: last group updating node
    __shared__ unsigned char  s_inv[Gn][Ln];  // 16KB: node -> base pos, per group
    __shared__ float4         s_xp[LPB];      // 1KB: x_pred cols, this block
    __shared__ float          s_part[NWV][Pn];
    __shared__ int            s_cnt;

    const float* xpb = xpred + (size_t)b * Ln * 3;
    const float* xnb = xnat  + (size_t)b * Ln * 3;

    // ---- prologue ----
    for (int l = tid; l < Ln; l += NTH) {
        s_idx[l]   = (unsigned short)l;
        s_stamp[l] = -1;
    }
    s_inv[wv][autom[wv * PK + lane]] = (unsigned char)lane;  // wave w: group w
    if (wv == 0) {
        const int l = c * LPB + lane;
        s_xp[lane] = make_float4(xpb[l * 3 + 0], xpb[l * 3 + 1], xpb[l * 3 + 2], 0.0f);
    }
    if (tid == 0) s_cnt = 0;

    int   a0k = autom[lane];                  // group-0 base node (identity map)
    float px = xpb[a0k * 3 + 0], py = xpb[a0k * 3 + 1], pz = xpb[a0k * 3 + 2];
    float nkx = xnb[a0k * 3 + 0], nky = xnb[a0k * 3 + 1], nkz = xnb[a0k * 3 + 2];
    unsigned short jl[LPW];
    #pragma unroll
    for (int i = 0; i < LPW; i++) jl[i] = (unsigned short)(c * LPB + wv * LPW + i);
    __syncthreads();

    int sig[Pn];
    #pragma unroll
    for (int p = 0; p < Pn; p++) sig[p] = 4 * (int)s_inv[0][autom[p * Kn + lane]];

    #pragma unroll 1
    for (int g = 0; g < Gn; g++) {
        const bool hn  = (g < Gn - 1);
        const int* ag  = autom + g * PK;
        const int* ag1 = ag + PK;             // only deref'd when hn
        ull* pg = part + (size_t)(g * Bn + b) * (BPB * Pn);

        // ---- compute: dn shared across the 8 perms via bpermute (r14) ----
        float acc[Pn];
        #pragma unroll
        for (int p = 0; p < Pn; p++) acc[p] = 0.0f;

        #pragma unroll 2
        for (int i = 0; i < LPW; i++) {
            const int il = wv * LPW + i;
            const int l  = c * LPB + il;
            if (__ballot(a0k == l)) continue;     // colmask: l in base set

            const float4 q = s_xp[il];
            const int    j = jl[i];
            const float mx = xnb[j * 3 + 0], my = xnb[j * 3 + 1], mz = xnb[j * 3 + 2];

            const float dx = px - q.x, dy = py - q.y, dz = pz - q.z;
            const float dp = __builtin_amdgcn_sqrtf(dx * dx + dy * dy + dz * dz);
            const float ex = nkx - mx, ey = nky - my, ez = nkz - mz;
            const float dn = __builtin_amdgcn_sqrtf(ex * ex + ey * ey + ez * ez);

            #pragma unroll
            for (int p = 0; p < Pn; p++) {
                const float dns = __int_as_float(
                    __builtin_amdgcn_ds_bpermute(sig[p], __float_as_int(dn)));
                const float e = dp - dns;
                acc[p] += fminf(e * e, CLAMP_V);
            }
        }

        // ---- wave reduce, then last-arriver folds + publishes (no barrier) ----
        #pragma unroll
        for (int p = 0; p < Pn; p++) {
            const float v = wave_sum64(acc[p]);
            if (lane == 63) s_part[wv][p] = v;
        }
        int old = 0;
        if (lane == 63)   // acq_rel orders this wave's s_part writes vs counter
            old = __hip_atomic_fetch_add(&s_cnt, 1, __ATOMIC_ACQ_REL,
                                         __HIP_MEMORY_SCOPE_WORKGROUP);
        old = __shfl(old, 63, 64);
        if (old == NWV - 1) {   // last wave: fold 8x8 + publish + reset counter
            float v = s_part[lane >> 3][lane & 7];   // lane = (q<<3)|p
            v = swz_xor<0x201F>(v);                  // fold wave bit0
            v = swz_xor<0x401F>(v);                  // fold wave bit1
            v += __shfl(v, lane + 32, 64);           // fold wave bit2
            if (lane < 8)
                st_rlx64(&pg[c * Pn + lane],
                         ((ull)MAGIC(g) << 32) | (ull)__float_as_uint(v));
            if (lane == 0) s_cnt = 0;   // safe: all arrivals for g done
        }

        // ---- prefetch g+1 constants with PRE-update map (races with wave-0's
        //      scatter below; only group-g-stamped rows can be torn, and the
        //      post-barrier patch re-reads exactly those) ----
        int   a0k1 = 0;
        float px1 = 0, py1 = 0, pz1 = 0, nk1x = 0, nk1y = 0, nk1z = 0;
        unsigned short jl1[LPW];
        if (hn) {
            a0k1 = ag1[lane];
            px1 = xpb[a0k1 * 3 + 0]; py1 = xpb[a0k1 * 3 + 1]; pz1 = xpb[a0k1 * 3 + 2];
            const int jn = s_idx[a0k1];
            nk1x = xnb[jn * 3 + 0]; nk1y = xnb[jn * 3 + 1]; nk1z = xnb[jn * 3 + 2];
            #pragma unroll
            for (int i = 0; i < LPW; i++) jl1[i] = s_idx[c * LPB + wv * LPW + i];
        }

        // ---- wave 0: poll 32x8 tagged qwords, fold, argmin, update s_idx ----
        if (wv == 0) {
            const unsigned magic = MAGIC(g);
            ull q0 = 0, q1 = 0, q2 = 0, q3 = 0;
            bool r0 = false, r1 = false, r2 = false, r3 = false;
            for (;;) {
                if (!r0) { q0 = ld_rlx64(pg + lane);       r0 = (unsigned)(q0 >> 32) == magic; }
                if (!r1) { q1 = ld_rlx64(pg + lane + 64);  r1 = (unsigned)(q1 >> 32) == magic; }
                if (!r2) { q2 = ld_rlx64(pg + lane + 128); r2 = (unsigned)(q2 >> 32) == magic; }
                if (!r3) { q3 = ld_rlx64(pg + lane + 192); r3 = (unsigned)(q3 >> 32) == magic; }
                if (__ballot(!(r0 && r1 && r2 && r3)) == 0ull) break;
                __builtin_amdgcn_s_sleep(1);
            }
            float v = __uint_as_float((unsigned)q0) + __uint_as_float((unsigned)q1)
                    + __uint_as_float((unsigned)q2) + __uint_as_float((unsigned)q3);
            v = swz_xor<0x201F>(v);          // fold c bit (lane bit 3)
            v = swz_xor<0x401F>(v);          // fold c bit (lane bit 4)
            v += __shfl(v, lane + 32, 64);   // fold c bit (lane bit 5)
            float best = __shfl(v, 0, 64);
            int   bj   = 0;
            #pragma unroll
            for (int p = 1; p < Pn; p++) {
                const float t = __shfl(v, p, 64);
                if (t < best) { best = t; bj = p; }  // strict < == argmin tie rule
            }
            const unsigned short oldv = s_idx[ag[bj * Kn + lane]];  // gather then
            s_idx[ag[lane]]   = oldv;                               // scatter
            s_stamp[ag[lane]] = (signed char)g;
        }
        __syncthreads();   // the ONLY barrier: update + prefetches complete

        // ---- patch stamped rows, adopt constants, recompute sig (static) ----
        if (hn) {
            if (s_stamp[a0k1] == (signed char)g) {
                const int jn = s_idx[a0k1];
                nk1x = xnb[jn * 3 + 0]; nk1y = xnb[jn * 3 + 1]; nk1z = xnb[jn * 3 + 2];
            }
            #pragma unroll
            for (int i = 0; i < LPW; i++) {
                const int col = c * LPB + wv * LPW + i;
                if (s_stamp[col] == (signed char)g) jl1[i] = s_idx[col];
                jl[i] = jl1[i];
            }
            a0k = a0k1; px = px1; py = py1; pz = pz1;
            nkx = nk1x; nky = nk1y; nkz = nk1z;
            #pragma unroll
            for (int p = 0; p < Pn; p++)
                sig[p] = 4 * (int)s_inv[g + 1][ag1[p * Kn + lane]];
        }
    }

    // ---- epilogue: out = x_native[idx], mask[idx] ----
    const int l0 = c * LPB;
    if (tid < LPB * 3) {
        const int ll = tid / 3, coord = tid % 3;
        const int l  = l0 + ll;
        const int j  = s_idx[l];
        out_x[((size_t)b * Ln + l) * 3 + coord] = xnb[j * 3 + coord];
    } else if (tid < LPB * 4) {
        const int l = l0 + (tid - LPB * 3);
        const int j = s_idx[l];
        out_m[(size_t)b * Ln + l] = (float)mask_in[(size_t)b * Ln + j];
    }
}

// ---------------------------------------------------------------------------
extern "C" void kernel_launch(void* const* d_in, const int* in_sizes, int n_in,
                              void* d_out, int out_size, void* d_ws, size_t ws_size,
                              hipStream_t stream) {
    const float* xpred   = (const float*)d_in[0];  // (B,L,3) f32
    const float* xnat_in = (const float*)d_in[1];  // (B,L,3) f32
    const int*   mask_in = (const int*)  d_in[2];  // (B,L) bool -> int32
    const int*   autom   = (const int*)  d_in[3];  // (G,P,K) -> int32

    float* out_x = (float*)d_out;          // (B,L,3)
    float* out_m = out_x + Bn * Ln * 3;    // (B,L) as float 0/1

    ull* part = (ull*)d_ws;                // Gn*Bn*BPB*Pn qwords (128KB)

    fused_kernel<<<Bn * BPB, NTH, 0, stream>>>(
        xpred, xnat_in, mask_in, autom, out_x, out_m, part);
}

// Round 18
// 115.783 us; speedup vs baseline: 1.3403x; 1.0727x over previous
//
#include <hip/hip_runtime.h>
#include <math.h>

#define Bn 16
#define Ln 2048
#define Gn 8
#define Pn 8
#define Kn 64
#define CLAMP_V 15.0f

#define BPB 32              // blocks per batch
#define NTH 512             // threads per block = 8 waves
#define NWV (NTH / 64)      // 8 waves
#define LPB (Ln / BPB)      // 64 l's per block
#define LPW (LPB / NWV)     // 8 l's per wave
#define PK  (Pn * Kn)

// d_ws: part[Gn][Bn][BPB][Pn] qwords = {MAGIC(g)<<32 | f32 partial}.
// Harness 0xAA poison never matches a tag -> tagged partial IS the arrival
// signal; no init pass, no counters (round-10-proven protocol).
#define MAGIC(g) (0x5EED0000u | (unsigned)(g))

typedef unsigned long long ull;

// wave64 sum via DPP (VALU pipe, no LDS). Total lands in lane 63.
__device__ __forceinline__ float wave_sum64(float x) {
#define DPP_ADD(ctrl) \
    x += __int_as_float(__builtin_amdgcn_update_dpp(0, __float_as_int(x), ctrl, 0xf, 0xf, true))
    DPP_ADD(0x111);  // row_shr:1
    DPP_ADD(0x112);  // row_shr:2
    DPP_ADD(0x114);  // row_shr:4
    DPP_ADD(0x118);  // row_shr:8
    DPP_ADD(0x142);  // row_bcast:15
    DPP_ADD(0x143);  // row_bcast:31
#undef DPP_ADD
    return x;
}

template <int IMM>
__device__ __forceinline__ float swz_xor(float v) {
    return v + __int_as_float(__builtin_amdgcn_ds_swizzle(__float_as_int(v), IMM));
}
__device__ __forceinline__ ull ld_rlx64(const ull* p) {
    return __hip_atomic_load(p, __ATOMIC_RELAXED, __HIP_MEMORY_SCOPE_AGENT);
}
__device__ __forceinline__ void st_rlx64(ull* p, ull v) {
    __hip_atomic_store(p, v, __ATOMIC_RELAXED, __HIP_MEMORY_SCOPE_AGENT);
}

// ---------------------------------------------------------------------------
// EXACT REVERT to the round-14 kernel — measured best (63.9us kernel,
// 116.36us total). Structure: tagged-qword publish/poll sync (r10) +
// dn-sharing via ds_bpermute (r14: dn(node j, l) computed ONCE per (j,l);
// per p the permuted dn reaches lane k via one bpermute with static
// sig[p] = 4*inv_g(a[p][k]); inner (k,l) cost ~50 VALU + 2 sqrt + 8 bperm).
// Attempts that FAILED to beat this (all reverted):
//   r11 speculative cross-group compute (spills + longer serial chain)
//   r12 anti-phase stagger kick (no overlap materialized)
//   r15 BPB 32->16 skew-width cut (neutral -> skew not width-dominated)
//   r16 dual-batch interleave (max-of-64 skew + cross-chain coupling)
//   r17 last-arriver publish + prefetch/patch 1-barrier (per-wave overhead)
// Remaining budget: ~27us VALU issue + ~9us LDS-pipe bperm + ~28us
// publish->observe chain (8 serial coherence round trips inherent to the
// scan dependency) + ~52us harness launch overhead outside the kernel.
// ---------------------------------------------------------------------------
__global__ __launch_bounds__(NTH, 2) void fused_kernel(
    const float* __restrict__ xpred, const float* __restrict__ xnat,
    const int* __restrict__ mask_in, const int* __restrict__ autom,
    float* __restrict__ out_x, float* __restrict__ out_m,
    ull* __restrict__ part) {

    const int tid  = threadIdx.x;
    const int lane = tid & 63;       // k = base position
    const int wv   = tid >> 6;       // wave 0..7
    const int b    = blockIdx.x >> 5;         // batch
    const int c    = blockIdx.x & (BPB - 1);  // chunk within batch

    __shared__ float4         s_all[Ln];      // 32KB: whole-batch x_nat rows
    __shared__ unsigned short s_idx[Ln];      // 4KB: private permutation
    __shared__ unsigned char  s_inv[2][Ln];   // 4KB: node -> base position
    __shared__ float4         s_xp[LPB];      // 1KB: x_pred cols, this block
    __shared__ float          s_part[NWV][Pn];

    const float* xpb = xpred + (size_t)b * Ln * 3;
    const float* xnb = xnat  + (size_t)b * Ln * 3;

    // ---- prologue ----
    for (int l = tid; l < Ln; l += NTH) {
        s_idx[l] = (unsigned short)l;
        s_all[l] = make_float4(xnb[l * 3 + 0], xnb[l * 3 + 1], xnb[l * 3 + 2], 0.0f);
    }
    if (wv == 0) {
        const int l = c * LPB + lane;
        s_xp[lane] = make_float4(xpb[l * 3 + 0], xpb[l * 3 + 1], xpb[l * 3 + 2], 0.0f);
    } else if (wv == 2) {
        s_inv[0][autom[lane]] = (unsigned char)lane;   // group-0 inverse map
    }
    int   a0k = autom[lane];                 // group-0 base node of this lane
    float px = xpb[a0k * 3 + 0], py = xpb[a0k * 3 + 1], pz = xpb[a0k * 3 + 2];
    __syncthreads();

    #pragma unroll 1
    for (int g = 0; g < Gn; g++) {
        const int* ag  = autom + g * PK;
        const int* ag1 = autom + (g + 1) * PK;   // only read when g<7
        const int  cur = g & 1, nxt = cur ^ 1;
        ull* pg = part + (size_t)(g * Bn + b) * (BPB * Pn);

        // ---- per-group lane constants (post-update-(g-1) map) ----
        const float4 nk = s_all[s_idx[a0k]];     // native point of base pos k
        int sig[Pn];                             // bpermute byte addresses
        #pragma unroll
        for (int p = 0; p < Pn; p++)
            sig[p] = 4 * (int)s_inv[cur][ag[p * Kn + lane]];
        unsigned short jl[LPW];                  // hoisted column row-ids
        #pragma unroll
        for (int i = 0; i < LPW; i++)
            jl[i] = s_idx[c * LPB + wv * LPW + i];

        float acc[Pn];
        #pragma unroll
        for (int p = 0; p < Pn; p++) acc[p] = 0.0f;

        // ---- compute: dn shared across the 8 perms via bpermute ----
        #pragma unroll 2
        for (int i = 0; i < LPW; i++) {
            const int il = wv * LPW + i;
            const int l  = c * LPB + il;
            if (__ballot(a0k == l)) continue;    // colmask: l in base set (rare)

            const float4 q = s_xp[il];
            const float4 m = s_all[jl[i]];
            const float dx = px - q.x, dy = py - q.y, dz = pz - q.z;
            const float dp = __builtin_amdgcn_sqrtf(dx * dx + dy * dy + dz * dz);
            const float ex = nk.x - m.x, ey = nk.y - m.y, ez = nk.z - m.z;
            const float dn = __builtin_amdgcn_sqrtf(ex * ex + ey * ey + ez * ez);

            #pragma unroll
            for (int p = 0; p < Pn; p++) {
                const float dns = __int_as_float(
                    __builtin_amdgcn_ds_bpermute(sig[p], __float_as_int(dn)));
                const float e = dp - dns;
                acc[p] += fminf(e * e, CLAMP_V);
            }
        }

        // ---- wave reduce (DPP, VALU pipe) ----
        #pragma unroll
        for (int p = 0; p < Pn; p++) {
            const float v = wave_sum64(acc[p]);
            if (lane == 63) s_part[wv][p] = v;
        }
        __syncthreads();   // (A) s_part complete; compute done block-wide

        // ---- wave 0: fold 8 waves x 8 p, publish tagged qwords ASAP ----
        if (wv == 0) {
            float v = s_part[lane >> 3][lane & 7];   // lane = (q<<3)|p
            v = swz_xor<0x201F>(v);                  // fold q bit0 (xor 8)
            v = swz_xor<0x401F>(v);                  // fold q bit1 (xor 16)
            v += __shfl(v, lane + 32, 64);           // fold q bit2 (cross-half)
            if (lane < 8)
                st_rlx64(&pg[c * Pn + lane],
                         ((ull)MAGIC(g) << 32) | (ull)__float_as_uint(v));
        }

        // ---- prefetch next group's static state ----
        if (g < Gn - 1) {
            a0k = ag1[lane];
            px = xpb[a0k * 3 + 0]; py = xpb[a0k * 3 + 1]; pz = xpb[a0k * 3 + 2];
            if (wv == 2) s_inv[nxt][ag1[lane]] = (unsigned char)lane;
        }

        // ---- wave 0: poll tagged qwords, reduce, argmin, update s_idx ----
        if (wv == 0) {
            const unsigned magic = MAGIC(g);
            ull q0 = 0, q1 = 0, q2 = 0, q3 = 0;
            bool r0 = false, r1 = false, r2 = false, r3 = false;
            for (;;) {
                if (!r0) { q0 = ld_rlx64(pg + lane);       r0 = (unsigned)(q0 >> 32) == magic; }
                if (!r1) { q1 = ld_rlx64(pg + lane + 64);  r1 = (unsigned)(q1 >> 32) == magic; }
                if (!r2) { q2 = ld_rlx64(pg + lane + 128); r2 = (unsigned)(q2 >> 32) == magic; }
                if (!r3) { q3 = ld_rlx64(pg + lane + 192); r3 = (unsigned)(q3 >> 32) == magic; }
                if (__ballot(!(r0 && r1 && r2 && r3)) == 0ull) break;
                __builtin_amdgcn_s_sleep(1);
            }
            float v = __uint_as_float((unsigned)q0) + __uint_as_float((unsigned)q1)
                    + __uint_as_float((unsigned)q2) + __uint_as_float((unsigned)q3);
            v = swz_xor<0x201F>(v);          // fold c bit (lane bit 3)
            v = swz_xor<0x401F>(v);          // fold c bit (lane bit 4)
            v += __shfl(v, lane + 32, 64);   // fold c bit (lane bit 5)
            // lanes 0..7 hold total drms[p = lane]; argmin uniform via shfl
            float best = __shfl(v, 0, 64);
            int   bj   = 0;
            #pragma unroll
            for (int p = 1; p < Pn; p++) {
                const float t = __shfl(v, p, 64);
                if (t < best) { best = t; bj = p; }  // strict < == argmin tie rule
            }
            // permutation update (gather then scatter, in-wave DS order)
            const unsigned short oldv = s_idx[ag[bj * Kn + lane]];
            s_idx[ag[lane]] = oldv;
        }
        __syncthreads();   // (B) s_idx + s_inv[nxt] visible for next compute
    }

    // ---- epilogue: out = x_native[idx] (from LDS), mask[idx] ----
    const int l0 = c * LPB;
    if (tid < LPB * 3) {
        const int ll = tid / 3, coord = tid % 3;
        const int l  = l0 + ll;
        const float4 v = s_all[s_idx[l]];
        out_x[((size_t)b * Ln + l) * 3 + coord] =
            (coord == 0) ? v.x : ((coord == 1) ? v.y : v.z);
    } else if (tid < LPB * 4) {
        const int l = l0 + (tid - LPB * 3);
        const int j = s_idx[l];
        out_m[(size_t)b * Ln + l] = (float)mask_in[(size_t)b * Ln + j];
    }
}

// ---------------------------------------------------------------------------
extern "C" void kernel_launch(void* const* d_in, const int* in_sizes, int n_in,
                              void* d_out, int out_size, void* d_ws, size_t ws_size,
                              hipStream_t stream) {
    const float* xpred   = (const float*)d_in[0];  // (B,L,3) f32
    const float* xnat_in = (const float*)d_in[1];  // (B,L,3) f32
    const int*   mask_in = (const int*)  d_in[2];  // (B,L) bool -> int32
    const int*   autom   = (const int*)  d_in[3];  // (G,P,K) -> int32

    float* out_x = (float*)d_out;          // (B,L,3)
    float* out_m = out_x + Bn * Ln * 3;    // (B,L) as float 0/1

    ull* part = (ull*)d_ws;                // Gn*Bn*BPB*Pn qwords (256KB)

    fused_kernel<<<Bn * BPB, NTH, 0, stream>>>(
        xpred, xnat_in, mask_in, autom, out_x, out_m, part);
}